// Round 12
// baseline (349.239 us; speedup 1.0000x reference)
//
#include <hip/hip_runtime.h>
#include <hip/hip_fp16.h>
#include <math.h>

// Problem constants
constexpr int D     = 64;
constexpr int H     = 14;
constexpr int HP2   = 8;     // half2 stride per node row (32B)
constexpr int P     = 16;
constexpr int LATc  = 7;
constexpr int OUTW  = 30;
constexpr float SP_INV_1 = 0.5413248546129181f;
constexpr int BLK   = 256;

// Packed fp16 atomic add (memory-side RMW; header overload missing in ROCm 7.2)
__device__ __forceinline__ void pk_atomic_add_f16(__half2* addr, __half2 val) {
    unsigned int bits = *reinterpret_cast<unsigned int*>(&val);
    asm volatile("global_atomic_pk_add_f16 %0, %1, off"
                 :: "v"(addr), "v"(bits) : "memory");
}
__device__ __forceinline__ unsigned int ld_agent(const unsigned int* p) {
    return __hip_atomic_load(p, __ATOMIC_RELAXED, __HIP_MEMORY_SCOPE_AGENT);
}

// ---------------- D1: XW = fp16(X @ W1); zero Y1/Y2; init barrier ----------
// 2 threads per node (proven R10).
__global__ void dense_xw_kernel(const float* __restrict__ X,
                                const float* __restrict__ W1,
                                __half2* __restrict__ XW,
                                __half2* __restrict__ Y1,
                                __half2* __restrict__ Y2,
                                int* __restrict__ bar, int N) {
    if (blockIdx.x == 0 && threadIdx.x == 0) *bar = 0;
    __shared__ float w[D * H];
    for (int i = threadIdx.x; i < D * H; i += blockDim.x) w[i] = W1[i];
    __syncthreads();
    int t = blockIdx.x * blockDim.x + threadIdx.x;
    int n = t >> 1;
    int half = t & 1;
    if (n >= N) return;

    float acc[H];
#pragma unroll
    for (int j = 0; j < H; ++j) acc[j] = 0.f;
    const float4* xr = reinterpret_cast<const float4*>(X + (size_t)n * D) + half * 8;
#pragma unroll
    for (int d4 = 0; d4 < 8; ++d4) {
        float4 x = xr[d4];
        float xs[4] = {x.x, x.y, x.z, x.w};
#pragma unroll
        for (int k = 0; k < 4; ++k) {
            int d = half * 32 + d4 * 4 + k;
#pragma unroll
            for (int j = 0; j < H; ++j) acc[j] = fmaf(xs[k], w[d * H + j], acc[j]);
        }
    }
#pragma unroll
    for (int j = 0; j < H; ++j) acc[j] += __shfl_xor(acc[j], 1);

    __half2 ov[4];
    if (half == 0) {
        ov[0] = __floats2half2_rn(acc[0], acc[1]);
        ov[1] = __floats2half2_rn(acc[2], acc[3]);
        ov[2] = __floats2half2_rn(acc[4], acc[5]);
        ov[3] = __floats2half2_rn(acc[6], acc[7]);
    } else {
        ov[0] = __floats2half2_rn(acc[8], acc[9]);
        ov[1] = __floats2half2_rn(acc[10], acc[11]);
        ov[2] = __floats2half2_rn(acc[12], acc[13]);
        ov[3] = __floats2half2_rn(0.f, 0.f);
    }
    reinterpret_cast<float4*>(XW + (size_t)n * HP2)[half] = *reinterpret_cast<float4*>(ov);
    float4 z = make_float4(0.f, 0.f, 0.f, 0.f);
    reinterpret_cast<float4*>(Y1 + (size_t)n * HP2)[half] = z;
    reinterpret_cast<float4*>(Y2 + (size_t)n * HP2)[half] = z;
}

// ---------------- D2: mega: spmm1 -> grid barrier -> fused hw+spmm2 --------
// Grid-stride everywhere; NO early returns (all threads reach the barrier).
__global__ __launch_bounds__(BLK, 4) void spmm_mega_kernel(
        const __half2* __restrict__ XW,
        const int* __restrict__ rows,
        const int* __restrict__ cols,
        const float* __restrict__ vals,
        const float* __restrict__ W2,
        __half2* __restrict__ Y1,
        __half2* __restrict__ Y2,
        int* __restrict__ bar,
        int E, int nblk) {
    __shared__ float w2s[H * H];
    for (int i = threadIdx.x; i < H * H; i += BLK) w2s[i] = W2[i];
    __syncthreads();

    const int tid = blockIdx.x * BLK + threadIdx.x;
    const int nth = gridDim.x * BLK;          // multiple of 8 -> f invariant
    const long long tot = (long long)E * 8;

    // ---- phase 1: Y1 += vals * XW[cols] ----
    for (long long i = tid; i < tot; i += nth) {
        int e = (int)(i >> 3), f = (int)(i & 7);
        if (f < 7) {
            int r = rows[e], c = cols[e];
            float v = vals[e];
            float2 xf = __half22float2(XW[c * HP2 + f]);
            __half2 p = __floats2half2_rn(v * xf.x, v * xf.y);
            pk_atomic_add_f16(&Y1[r * HP2 + f], p);
        }
    }

    // ---- grid barrier (single monotone counter, zeroed by D1) ----
    __syncthreads();   // drains vmcnt -> this block's atomics are complete
    if (threadIdx.x == 0) {
        __hip_atomic_fetch_add(bar, 1, __ATOMIC_ACQ_REL, __HIP_MEMORY_SCOPE_AGENT);
        while (__hip_atomic_load(bar, __ATOMIC_ACQUIRE, __HIP_MEMORY_SCOPE_AGENT) < nblk)
            __builtin_amdgcn_s_sleep(1);
    }
    __syncthreads();

    // ---- phase 2: Y2 += vals * (relu(Y1[cols]) @ W2), HW on the fly ----
    const int fslot = tid & 7;
    float w2a[H], w2b[H];
    if (fslot < 7) {
#pragma unroll
        for (int i = 0; i < H; ++i) {
            w2a[i] = w2s[i * H + 2 * fslot];
            w2b[i] = w2s[i * H + 2 * fslot + 1];
        }
    }
    const unsigned int* Y1u = reinterpret_cast<const unsigned int*>(Y1);
    for (long long i = tid; i < tot; i += nth) {
        int e = (int)(i >> 3), f = (int)(i & 7);
        if (f < 7) {
            int r = rows[e], c = cols[e];
            float v = vals[e];
            const unsigned int* yrow = Y1u + (size_t)c * HP2;
            float h[H];
#pragma unroll
            for (int k = 0; k < 7; ++k) {
                unsigned int u = ld_agent(&yrow[k]);   // bypass stale L1/L2
                float2 t2 = __half22float2(*reinterpret_cast<__half2*>(&u));
                h[2 * k]     = fmaxf(t2.x, 0.f);
                h[2 * k + 1] = fmaxf(t2.y, 0.f);
            }
            float a0 = 0.f, a1 = 0.f;
#pragma unroll
            for (int i2 = 0; i2 < H; ++i2) {
                a0 = fmaf(h[i2], w2a[i2], a0);
                a1 = fmaf(h[i2], w2b[i2], a1);
            }
            __half2 p = __floats2half2_rn(v * a0, v * a1);
            pk_atomic_add_f16(&Y2[r * HP2 + f], p);
        }
    }
}

// ---------------- D3: fused tail with LDS-staged coalesced output ----------
__global__ __launch_bounds__(256) void final_kernel(
        const __half2* __restrict__ Y2,
        const float* __restrict__ Wd1,
        const float* __restrict__ bd1,
        const float* __restrict__ Wd2,
        const float* __restrict__ bd2,
        float* __restrict__ out, int N) {
    __shared__ float wd1[H * H], wd2[H * P], b1[H], b2[P];
    __shared__ float so[256 * OUTW];
    for (int i = threadIdx.x; i < H * H; i += 256) wd1[i] = Wd1[i];
    for (int i = threadIdx.x; i < H * P; i += 256) wd2[i] = Wd2[i];
    if (threadIdx.x < H) b1[threadIdx.x] = bd1[threadIdx.x];
    if (threadIdx.x < P) b2[threadIdx.x] = bd2[threadIdx.x];
    __syncthreads();

    int base = blockIdx.x * 256;
    int n = base + threadIdx.x;
    if (n < N) {
        const float4* yr4 = reinterpret_cast<const float4*>(Y2 + (size_t)n * HP2);
        float4 ya = yr4[0], yb = yr4[1];
        __half2 yh[HP2];
        *reinterpret_cast<float4*>(&yh[0]) = ya;
        *reinterpret_cast<float4*>(&yh[4]) = yb;
        float h[H];
#pragma unroll
        for (int k = 0; k < 7; ++k) {
            float2 t = __half22float2(yh[k]);
            h[2 * k]     = fmaxf(t.x, 0.f);
            h[2 * k + 1] = fmaxf(t.y, 0.f);
        }
        float* so_row = &so[threadIdx.x * OUTW];
        float pd7[LATc];
#pragma unroll
        for (int j = 0; j < H; ++j) {
            float a = b1[j];
#pragma unroll
            for (int i = 0; i < H; ++i) a = fmaf(h[i], wd1[i * H + j], a);
            float t = tanhf(a);
            if (j < LATc) so_row[j] = t;
            else pd7[j - LATc] = t;
        }
#pragma unroll
        for (int k = 0; k < LATc; ++k) {
            float x = pd7[k] + SP_INV_1;
            so_row[LATc + k] = log1pf(expf(x));
        }
#pragma unroll
        for (int j = 0; j < P; ++j) {
            float a = b2[j];
#pragma unroll
            for (int i = 0; i < H; ++i) a = fmaf(h[i], wd2[i * P + j], a);
            so_row[14 + j] = tanhf(a);
        }
    }
    __syncthreads();

    int rowsHere = N - base;
    if (rowsHere > 256) rowsHere = 256;
    if (rowsHere < 0) rowsHere = 0;
    int cnt = rowsHere * OUTW;
    float* obase = out + (size_t)base * OUTW;
    for (int i = threadIdx.x; i < cnt; i += 256) obase[i] = so[i];
}

extern "C" void kernel_launch(void* const* d_in, const int* in_sizes, int n_in,
                              void* d_out, int out_size, void* d_ws, size_t ws_size,
                              hipStream_t stream) {
    const float* X    = (const float*)d_in[0];
    const int*   rows = (const int*)d_in[1];
    const int*   cols = (const int*)d_in[2];
    const float* vals = (const float*)d_in[3];
    const float* W1   = (const float*)d_in[4];
    const float* W2   = (const float*)d_in[5];
    const float* Wd1  = (const float*)d_in[6];
    const float* bd1  = (const float*)d_in[7];
    const float* Wd2  = (const float*)d_in[8];
    const float* bd2  = (const float*)d_in[9];
    float* out = (float*)d_out;

    const int N = in_sizes[0] / D;   // 100000
    const int E = in_sizes[1];       // 1000000

    // workspace: XW | Y1 | Y2 (half2 rows, 32B/node) | bar (int)
    __half2* XW = (__half2*)d_ws;
    __half2* Y1 = XW + (size_t)N * HP2;
    __half2* Y2 = Y1 + (size_t)N * HP2;
    int* bar = (int*)(Y2 + (size_t)N * HP2);

    // Size mega grid from occupancy (host query, deterministic, capture-safe)
    int blocksPerCU = 0;
    (void)hipOccupancyMaxActiveBlocksPerMultiprocessor(
        &blocksPerCU, (const void*)spmm_mega_kernel, BLK, 0);
    int numCU = 0;
    (void)hipDeviceGetAttribute(&numCU, hipDeviceAttributeMultiprocessorCount, 0);
    int grid = (blocksPerCU > 0 && numCU > 0) ? blocksPerCU * numCU : 1024;
    if (grid > 4096) grid = 4096;

    int blkN  = (N + 255) / 256;
    int blkN2 = (2 * N + 255) / 256;

    dense_xw_kernel<<<blkN2, 256, 0, stream>>>(X, W1, XW, Y1, Y2, bar, N);
    spmm_mega_kernel<<<grid, BLK, 0, stream>>>(XW, rows, cols, vals, W2,
                                               Y1, Y2, bar, E, grid);
    final_kernel<<<blkN, 256, 0, stream>>>(Y2, Wd1, bd1, Wd2, bd2, out, N);
}